// Round 7
// baseline (602.821 us; speedup 1.0000x reference)
//
#include <hip/hip_runtime.h>
#include <hip/hip_cooperative_groups.h>

namespace cg = cooperative_groups;

#define D 128

typedef short s16x8 __attribute__((ext_vector_type(8)));
typedef float f32x4 __attribute__((ext_vector_type(4)));

static __device__ __forceinline__ float bf2f(ushort h) {
    return __uint_as_float(((uint)h) << 16);
}
static __device__ __forceinline__ ushort f2bf(float f) {
    uint u = __float_as_uint(f);
    u += 0x7fffu + ((u >> 16) & 1u);   // RNE
    return (ushort)(u >> 16);
}

// ================= cooperative build: zero -> convert/count/pack -> alloc -> fill -> gather =================
// All phases are low-VGPR, no-LDS; __launch_bounds__(256,4) caps VGPR at 128 so
// 1024 blocks (4/CU) are co-resident for grid.sync().
__global__ __launch_bounds__(256, 4)
void build_kernel(const float4* __restrict__ x4, ushort* __restrict__ xh, int n4,
                  const int* __restrict__ src, const int* __restrict__ dst, int E,
                  const float* __restrict__ W1, const float* __restrict__ W2,
                  ushort* __restrict__ wp,
                  int* __restrict__ cnt, int* __restrict__ tot,
                  int* __restrict__ startA, int* __restrict__ cur,
                  int* __restrict__ bucket, float* __restrict__ stats,
                  ushort* __restrict__ z, int N) {
    cg::grid_group grid = cg::this_grid();
    int tid = blockIdx.x * blockDim.x + threadIdx.x;
    int gsz = gridDim.x * blockDim.x;

    // ---- phase 0: zero cnt/stats/tot ----
    for (int i = tid; i < N; i += gsz) cnt[i] = 0;
    if (tid < 256) stats[tid] = 0.f;
    if (tid == 0) *tot = 0;
    grid.sync();

    // ---- phase 1: x->bf16, degree count, W pack ----
    {
        ushort4* xh4 = (ushort4*)xh;
        for (int i = tid; i < n4; i += gsz) {
            float4 v = x4[i];
            ushort4 h;
            h.x = f2bf(v.x); h.y = f2bf(v.y); h.z = f2bf(v.z); h.w = f2bf(v.w);
            xh4[i] = h;
        }
        for (int e = tid; e < E; e += gsz) atomicAdd(&cnt[dst[e]], 1);
        // W B-fragment layout (mfma_f32_16x16x32_bf16): lane l, elem i holds
        // W[ks*32 + (l>>4)*8 + i][nf*16 + (l&15)], packed at ((ks*8+nf)*64+lane)*8+i.
        if (tid < 4096) {
            int m = tid >> 11;
            int r = tid & 2047;
            int lane = r & 63;
            int nf = (r >> 6) & 7;
            int ks = r >> 9;
            const float* W = m ? W2 : W1;
            ushort* o = wp + m * 16384;
            int k0 = ks * 32 + ((lane >> 4) << 3);
            int c = nf * 16 + (lane & 15);
            #pragma unroll
            for (int i = 0; i < 8; ++i) o[r * 8 + i] = f2bf(W[(k0 + i) * D + c]);
        }
    }
    grid.sync();

    // ---- phase 2: alloc (wave-scan + one atomic per wave; regions contiguous per node) ----
    for (int i0 = 0; i0 < N; i0 += gsz) {
        int i = i0 + tid;
        int lane = threadIdx.x & 63;
        int c = (i < N) ? cnt[i] : 0;
        int inc = c;
        #pragma unroll
        for (int s = 1; s < 64; s <<= 1) {
            int u = __shfl_up(inc, (unsigned)s);
            if (lane >= s) inc += u;
        }
        int base = 0;
        if (lane == 63) base = atomicAdd(tot, inc);
        base = __shfl(base, 63);
        if (i < N) { int st = base + inc - c; startA[i] = st; cur[i] = st; }
    }
    grid.sync();

    // ---- phase 3: fill buckets ----
    for (int e = tid; e < E; e += gsz) {
        int p = atomicAdd(&cur[dst[e]], 1);
        bucket[p] = src[e];
    }
    grid.sync();

    // ---- phase 4: gather  z = xh + segment_sum(xh[src]) ----
    // half-wave (32 lanes, 8B/lane) per node, 8-deep unroll for MLP.
    {
        const ushort4* xh4 = (const ushort4*)xh;
        ushort4* z4 = (ushort4*)z;
        int lane = threadIdx.x & 31;
        int sub = threadIdx.x >> 5;   // 0..7
        for (int nb = blockIdx.x * 8; nb < N; nb += gridDim.x * 8) {
            int node = nb + sub;
            if (node >= N) continue;
            int e0 = startA[node];
            int eend = e0 + cnt[node];
            float a0 = 0.f, a1 = 0.f, a2 = 0.f, a3 = 0.f;
            int e = e0;
            for (; e + 8 <= eend; e += 8) {
                int s0 = bucket[e],     s1 = bucket[e + 1], s2 = bucket[e + 2], s3 = bucket[e + 3];
                int s4 = bucket[e + 4], s5 = bucket[e + 5], s6 = bucket[e + 6], s7 = bucket[e + 7];
                ushort4 v0 = xh4[(size_t)s0 * 32 + lane];
                ushort4 v1 = xh4[(size_t)s1 * 32 + lane];
                ushort4 v2 = xh4[(size_t)s2 * 32 + lane];
                ushort4 v3 = xh4[(size_t)s3 * 32 + lane];
                ushort4 v4 = xh4[(size_t)s4 * 32 + lane];
                ushort4 v5 = xh4[(size_t)s5 * 32 + lane];
                ushort4 v6 = xh4[(size_t)s6 * 32 + lane];
                ushort4 v7 = xh4[(size_t)s7 * 32 + lane];
                a0 += bf2f(v0.x) + bf2f(v1.x) + bf2f(v2.x) + bf2f(v3.x)
                    + bf2f(v4.x) + bf2f(v5.x) + bf2f(v6.x) + bf2f(v7.x);
                a1 += bf2f(v0.y) + bf2f(v1.y) + bf2f(v2.y) + bf2f(v3.y)
                    + bf2f(v4.y) + bf2f(v5.y) + bf2f(v6.y) + bf2f(v7.y);
                a2 += bf2f(v0.z) + bf2f(v1.z) + bf2f(v2.z) + bf2f(v3.z)
                    + bf2f(v4.z) + bf2f(v5.z) + bf2f(v6.z) + bf2f(v7.z);
                a3 += bf2f(v0.w) + bf2f(v1.w) + bf2f(v2.w) + bf2f(v3.w)
                    + bf2f(v4.w) + bf2f(v5.w) + bf2f(v6.w) + bf2f(v7.w);
            }
            for (; e + 4 <= eend; e += 4) {
                int s0 = bucket[e], s1 = bucket[e + 1], s2 = bucket[e + 2], s3 = bucket[e + 3];
                ushort4 v0 = xh4[(size_t)s0 * 32 + lane];
                ushort4 v1 = xh4[(size_t)s1 * 32 + lane];
                ushort4 v2 = xh4[(size_t)s2 * 32 + lane];
                ushort4 v3 = xh4[(size_t)s3 * 32 + lane];
                a0 += bf2f(v0.x) + bf2f(v1.x) + bf2f(v2.x) + bf2f(v3.x);
                a1 += bf2f(v0.y) + bf2f(v1.y) + bf2f(v2.y) + bf2f(v3.y);
                a2 += bf2f(v0.z) + bf2f(v1.z) + bf2f(v2.z) + bf2f(v3.z);
                a3 += bf2f(v0.w) + bf2f(v1.w) + bf2f(v2.w) + bf2f(v3.w);
            }
            for (; e < eend; ++e) {
                int s = bucket[e];
                ushort4 v = xh4[(size_t)s * 32 + lane];
                a0 += bf2f(v.x); a1 += bf2f(v.y); a2 += bf2f(v.z); a3 += bf2f(v.w);
            }
            ushort4 xv = xh4[(size_t)node * 32 + lane];
            ushort4 zo;
            zo.x = f2bf(a0 + bf2f(xv.x)); zo.y = f2bf(a1 + bf2f(xv.y));
            zo.z = f2bf(a2 + bf2f(xv.z)); zo.w = f2bf(a3 + bf2f(xv.w));
            z4[(size_t)node * 32 + lane] = zo;
        }
    }
}

// ================= GEMM1: h1 = relu(z @ W1 + b1), bf16 out (W1 in LDS) =================
__global__ __launch_bounds__(256, 4)
void gemm1_kernel(const ushort* __restrict__ Z, const ushort* __restrict__ Wp,
                  const float* __restrict__ bias, ushort* __restrict__ H1, int nTiles) {
    __shared__ ushort Ws[16384];   // 32 KB
    {
        const float4* g = (const float4*)Wp;
        float4* l = (float4*)Ws;
        for (int i = threadIdx.x; i < 2048; i += 256) l[i] = g[i];
    }
    __syncthreads();
    int wave = threadIdx.x >> 6, lane = threadIdx.x & 63;
    int rsel = lane & 15;
    int csel = lane >> 4;
    for (int tile = blockIdx.x * 4 + wave; tile < nTiles; tile += gridDim.x * 4) {
        int row0 = tile * 16;
        const ushort* aP = Z + (size_t)(row0 + rsel) * D + csel * 8;
        f32x4 acc[8];
        #pragma unroll
        for (int nf = 0; nf < 8; ++nf) acc[nf] = (f32x4){0.f, 0.f, 0.f, 0.f};
        #pragma unroll
        for (int ks = 0; ks < 4; ++ks) {
            s16x8 a = *(const s16x8*)(aP + ks * 32);
            #pragma unroll
            for (int nf = 0; nf < 8; ++nf) {
                s16x8 b = *(const s16x8*)(&Ws[((ks * 8 + nf) * 64 + lane) * 8]);
                acc[nf] = __builtin_amdgcn_mfma_f32_16x16x32_bf16(a, b, acc[nf], 0, 0, 0);
            }
        }
        int orow0 = row0 + csel * 4;
        #pragma unroll
        for (int nf = 0; nf < 8; ++nf) {
            int col = nf * 16 + rsel;
            float bb = bias[col];
            #pragma unroll
            for (int r = 0; r < 4; ++r) {
                float v = fmaxf(acc[nf][r] + bb, 0.f);
                H1[(size_t)(orow0 + r) * D + col] = f2bf(v);
            }
        }
    }
}

// ================= GEMM2: out = h1 @ W2 + b2 (fp32) + fused BN stats (W2 in LDS) =================
__global__ __launch_bounds__(256, 4)
void gemm2_kernel(const ushort* __restrict__ H1, const ushort* __restrict__ Wp,
                  const float* __restrict__ bias, float* __restrict__ out,
                  float* __restrict__ stats, int nTiles) {
    __shared__ ushort Ws[16384];   // 32 KB
    __shared__ float sred[256];
    sred[threadIdx.x] = 0.f;
    {
        const float4* g = (const float4*)Wp;
        float4* l = (float4*)Ws;
        for (int i = threadIdx.x; i < 2048; i += 256) l[i] = g[i];
    }
    __syncthreads();
    int wave = threadIdx.x >> 6, lane = threadIdx.x & 63;
    int rsel = lane & 15;
    int csel = lane >> 4;
    for (int tile = blockIdx.x * 4 + wave; tile < nTiles; tile += gridDim.x * 4) {
        int row0 = tile * 16;
        const ushort* aP = H1 + (size_t)(row0 + rsel) * D + csel * 8;
        f32x4 acc[8];
        #pragma unroll
        for (int nf = 0; nf < 8; ++nf) acc[nf] = (f32x4){0.f, 0.f, 0.f, 0.f};
        #pragma unroll
        for (int ks = 0; ks < 4; ++ks) {
            s16x8 a = *(const s16x8*)(aP + ks * 32);
            #pragma unroll
            for (int nf = 0; nf < 8; ++nf) {
                s16x8 b = *(const s16x8*)(&Ws[((ks * 8 + nf) * 64 + lane) * 8]);
                acc[nf] = __builtin_amdgcn_mfma_f32_16x16x32_bf16(a, b, acc[nf], 0, 0, 0);
            }
        }
        int orow0 = row0 + csel * 4;
        #pragma unroll
        for (int nf = 0; nf < 8; ++nf) {
            int col = nf * 16 + rsel;
            float bb = bias[col];
            float ps = 0.f, pq = 0.f;
            #pragma unroll
            for (int r = 0; r < 4; ++r) {
                float v = acc[nf][r] + bb;
                out[(size_t)(orow0 + r) * D + col] = v;
                ps += v; pq += v * v;
            }
            ps += __shfl_xor(ps, 16); ps += __shfl_xor(ps, 32);
            pq += __shfl_xor(pq, 16); pq += __shfl_xor(pq, 32);
            if (csel == 0) {
                atomicAdd(&sred[col], ps);
                atomicAdd(&sred[128 + col], pq);
            }
        }
    }
    __syncthreads();
    if (threadIdx.x < 256) atomicAdd(&stats[threadIdx.x], sred[threadIdx.x]);
}

// ================= BN normalize + residual =================
__global__ void bn_final(float4* __restrict__ out4, const float4* __restrict__ x4,
                         const float* __restrict__ stats, const float* __restrict__ gamma,
                         const float* __restrict__ beta, int n4, float invN) {
    int i = blockIdx.x * blockDim.x + threadIdx.x;
    if (i >= n4) return;
    int cc = i & 31;
    const float4* s4 = (const float4*)stats;
    float4 sum = s4[cc], sq = s4[32 + cc];
    float4 g = ((const float4*)gamma)[cc], b = ((const float4*)beta)[cc];
    float4 h = out4[i], xx = x4[i];
    float4 o;
    {
        float m = sum.x * invN, v = sq.x * invN - m * m, iv = rsqrtf(v + 1e-5f);
        o.x = (h.x - m) * iv * g.x + b.x + xx.x;
    }
    {
        float m = sum.y * invN, v = sq.y * invN - m * m, iv = rsqrtf(v + 1e-5f);
        o.y = (h.y - m) * iv * g.y + b.y + xx.y;
    }
    {
        float m = sum.z * invN, v = sq.z * invN - m * m, iv = rsqrtf(v + 1e-5f);
        o.z = (h.z - m) * iv * g.z + b.z + xx.z;
    }
    {
        float m = sum.w * invN, v = sq.w * invN - m * m, iv = rsqrtf(v + 1e-5f);
        o.w = (h.w - m) * iv * g.w + b.w + xx.w;
    }
    out4[i] = o;
}

extern "C" void kernel_launch(void* const* d_in, const int* in_sizes, int n_in,
                              void* d_out, int out_size, void* d_ws, size_t ws_size,
                              hipStream_t stream) {
    const float* x     = (const float*)d_in[0];
    const int*   ei    = (const int*)d_in[1];
    const float* W1    = (const float*)d_in[2];
    const float* b1    = (const float*)d_in[3];
    const float* W2    = (const float*)d_in[4];
    const float* b2    = (const float*)d_in[5];
    const float* gamma = (const float*)d_in[6];
    const float* beta  = (const float*)d_in[7];
    float* out = (float*)d_out;

    int N = in_sizes[0] / D;   // 50000
    int E = in_sizes[1] / 2;   // 600000
    const int* src = ei;
    const int* dst = ei + E;

    size_t NB = (size_t)N * D;
    ushort* xh   = (ushort*)d_ws;          // NB ushorts
    ushort* z    = xh + NB;                // NB ushorts
    ushort* h1   = z + NB;                 // NB ushorts
    ushort* wp   = h1 + NB;                // 2*16384
    float*  stats = (float*)(wp + 32768);  // 256 floats (16B aligned)
    int*    cnt  = (int*)(stats + 256);    // N
    int*    tot  = cnt + N;                // 1
    int*    startA = tot + 1;              // N
    int*    cur  = startA + N;             // N
    int*    bucket = cur + N;              // E

    int n4 = (int)(NB / 4);

    // ---- cooperative build: zero -> convert/count/pack -> alloc -> fill -> gather ----
    {
        const float4* x4p = (const float4*)x;
        void* args[] = {
            (void*)&x4p, (void*)&xh, (void*)&n4,
            (void*)&src, (void*)&dst, (void*)&E,
            (void*)&W1, (void*)&W2, (void*)&wp,
            (void*)&cnt, (void*)&tot, (void*)&startA, (void*)&cur,
            (void*)&bucket, (void*)&stats, (void*)&z, (void*)&N
        };
        hipLaunchCooperativeKernel((const void*)build_kernel, dim3(1024), dim3(256),
                                   args, 0, stream);
    }

    const int B = 256;
    int nTiles = (N + 15) / 16;   // 3125
    gemm1_kernel<<<1024, B, 0, stream>>>(z, wp, b1, h1, nTiles);
    gemm2_kernel<<<1024, B, 0, stream>>>(h1, wp + 16384, b2, out, stats, nTiles);
    bn_final<<<(n4 + B - 1) / B, B, 0, stream>>>((float4*)out, (const float4*)x, stats,
                                                 gamma, beta, n4, 1.0f / (float)N);
}

// Round 8
// 192.616 us; speedup vs baseline: 3.1296x; 3.1296x over previous
//
#include <hip/hip_runtime.h>

#define D 128

typedef short s16x8 __attribute__((ext_vector_type(8)));
typedef ushort u16x8 __attribute__((ext_vector_type(8)));
typedef float f32x4 __attribute__((ext_vector_type(4)));

static __device__ __forceinline__ float bf2f(ushort h) {
    return __uint_as_float(((uint)h) << 16);
}
static __device__ __forceinline__ ushort f2bf(float f) {
    uint u = __float_as_uint(f);
    u += 0x7fffu + ((u >> 16) & 1u);   // RNE
    return (ushort)(u >> 16);
}

// ---------------- prep: x->bf16  +  degree count  +  W pack ----------------
// W B-fragment layout (mfma_f32_16x16x32_bf16): lane l, elem i holds
// W[ks*32 + (l>>4)*8 + i][nf*16 + (l&15)], packed at ((ks*8+nf)*64+lane)*8+i.
__global__ void prep_kernel(const float4* __restrict__ x4, ushort4* __restrict__ xh4, int n4,
                            const int* __restrict__ dst, int* __restrict__ cnt, int E,
                            const float* __restrict__ W1, const float* __restrict__ W2,
                            ushort* __restrict__ wp) {
    int tid = blockIdx.x * blockDim.x + threadIdx.x;
    int stride = gridDim.x * blockDim.x;
    for (int i = tid; i < n4; i += stride) {
        float4 v = x4[i];
        ushort4 h;
        h.x = f2bf(v.x); h.y = f2bf(v.y); h.z = f2bf(v.z); h.w = f2bf(v.w);
        xh4[i] = h;
    }
    for (int e = tid; e < E; e += stride) atomicAdd(&cnt[dst[e]], 1);
    if (tid < 4096) {
        int m = tid >> 11;
        int r = tid & 2047;
        int lane = r & 63;
        int nf = (r >> 6) & 7;
        int ks = r >> 9;
        const float* W = m ? W2 : W1;
        ushort* o = wp + m * 16384;
        int k0 = ks * 32 + ((lane >> 4) << 3);
        int c = nf * 16 + (lane & 15);
        #pragma unroll
        for (int i = 0; i < 8; ++i) o[r * 8 + i] = f2bf(W[(k0 + i) * D + c]);
    }
}

// ---------------- CSR alloc + fill ----------------
__global__ void alloc_kernel(const int* __restrict__ cnt, int* __restrict__ start,
                             int* __restrict__ cur, int* __restrict__ total, int n) {
    int i = blockIdx.x * blockDim.x + threadIdx.x;
    int lane = threadIdx.x & 63;
    int c = (i < n) ? cnt[i] : 0;
    int inc = c;
    #pragma unroll
    for (int s = 1; s < 64; s <<= 1) {
        int u = __shfl_up(inc, (unsigned)s);
        if (lane >= s) inc += u;
    }
    int base = 0;
    if (lane == 63) base = atomicAdd(total, inc);
    base = __shfl(base, 63);
    if (i < n) { int st = base + inc - c; start[i] = st; cur[i] = st; }
}

__global__ void fill_kernel(const int* __restrict__ src, const int* __restrict__ dst,
                            int* __restrict__ cur, int* __restrict__ bucket, int E) {
    int e = blockIdx.x * blockDim.x + threadIdx.x;
    if (e < E) {
        int p = atomicAdd(&cur[dst[e]], 1);
        bucket[p] = src[e];
    }
}

// ---------------- gather: z = xh + segment_sum(xh[src]) -> bf16 ----------------
// quarter-wave (16 lanes x 16B ushort8) per node: 4 independent edge-chains per
// wave (2x the outstanding loads of the half-wave version) for this
// latency-bound kernel. 256B row = one coalesced load per 16-lane group.
__global__ void gather_kernel(const u16x8* __restrict__ xh8,
                              const int* __restrict__ start, const int* __restrict__ cnt,
                              const int* __restrict__ bucket,
                              u16x8* __restrict__ z8, int n) {
    int node = blockIdx.x * 16 + (threadIdx.x >> 4);
    int lane = threadIdx.x & 15;
    if (node >= n) return;
    int e0 = start[node];
    int eend = e0 + cnt[node];
    float a[8];
    #pragma unroll
    for (int j = 0; j < 8; ++j) a[j] = 0.f;
    int e = e0;
    for (; e + 8 <= eend; e += 8) {
        int s0 = bucket[e],     s1 = bucket[e + 1], s2 = bucket[e + 2], s3 = bucket[e + 3];
        int s4 = bucket[e + 4], s5 = bucket[e + 5], s6 = bucket[e + 6], s7 = bucket[e + 7];
        u16x8 v0 = xh8[(size_t)s0 * 16 + lane];
        u16x8 v1 = xh8[(size_t)s1 * 16 + lane];
        u16x8 v2 = xh8[(size_t)s2 * 16 + lane];
        u16x8 v3 = xh8[(size_t)s3 * 16 + lane];
        u16x8 v4 = xh8[(size_t)s4 * 16 + lane];
        u16x8 v5 = xh8[(size_t)s5 * 16 + lane];
        u16x8 v6 = xh8[(size_t)s6 * 16 + lane];
        u16x8 v7 = xh8[(size_t)s7 * 16 + lane];
        #pragma unroll
        for (int j = 0; j < 8; ++j) {
            a[j] += bf2f(v0[j]) + bf2f(v1[j]) + bf2f(v2[j]) + bf2f(v3[j])
                  + bf2f(v4[j]) + bf2f(v5[j]) + bf2f(v6[j]) + bf2f(v7[j]);
        }
    }
    for (; e + 4 <= eend; e += 4) {
        int s0 = bucket[e], s1 = bucket[e + 1], s2 = bucket[e + 2], s3 = bucket[e + 3];
        u16x8 v0 = xh8[(size_t)s0 * 16 + lane];
        u16x8 v1 = xh8[(size_t)s1 * 16 + lane];
        u16x8 v2 = xh8[(size_t)s2 * 16 + lane];
        u16x8 v3 = xh8[(size_t)s3 * 16 + lane];
        #pragma unroll
        for (int j = 0; j < 8; ++j)
            a[j] += bf2f(v0[j]) + bf2f(v1[j]) + bf2f(v2[j]) + bf2f(v3[j]);
    }
    for (; e < eend; ++e) {
        int s = bucket[e];
        u16x8 v = xh8[(size_t)s * 16 + lane];
        #pragma unroll
        for (int j = 0; j < 8; ++j) a[j] += bf2f(v[j]);
    }
    u16x8 xv = xh8[(size_t)node * 16 + lane];
    u16x8 zo;
    #pragma unroll
    for (int j = 0; j < 8; ++j) zo[j] = f2bf(a[j] + bf2f(xv[j]));
    z8[(size_t)node * 16 + lane] = zo;
}

// ---------------- GEMM1: h1 = relu(z @ W1 + b1), bf16 out (W1 in LDS) ----------------
__global__ __launch_bounds__(256, 4)
void gemm1_kernel(const ushort* __restrict__ Z, const ushort* __restrict__ Wp,
                  const float* __restrict__ bias, ushort* __restrict__ H1, int nTiles) {
    __shared__ ushort Ws[16384];   // 32 KB
    {
        const float4* g = (const float4*)Wp;
        float4* l = (float4*)Ws;
        for (int i = threadIdx.x; i < 2048; i += 256) l[i] = g[i];
    }
    __syncthreads();
    int wave = threadIdx.x >> 6, lane = threadIdx.x & 63;
    int rsel = lane & 15;
    int csel = lane >> 4;
    for (int tile = blockIdx.x * 4 + wave; tile < nTiles; tile += gridDim.x * 4) {
        int row0 = tile * 16;
        const ushort* aP = Z + (size_t)(row0 + rsel) * D + csel * 8;
        f32x4 acc[8];
        #pragma unroll
        for (int nf = 0; nf < 8; ++nf) acc[nf] = (f32x4){0.f, 0.f, 0.f, 0.f};
        #pragma unroll
        for (int ks = 0; ks < 4; ++ks) {
            s16x8 a = *(const s16x8*)(aP + ks * 32);
            #pragma unroll
            for (int nf = 0; nf < 8; ++nf) {
                s16x8 b = *(const s16x8*)(&Ws[((ks * 8 + nf) * 64 + lane) * 8]);
                acc[nf] = __builtin_amdgcn_mfma_f32_16x16x32_bf16(a, b, acc[nf], 0, 0, 0);
            }
        }
        int orow0 = row0 + csel * 4;
        #pragma unroll
        for (int nf = 0; nf < 8; ++nf) {
            int col = nf * 16 + rsel;
            float bb = bias[col];
            #pragma unroll
            for (int r = 0; r < 4; ++r) {
                float v = fmaxf(acc[nf][r] + bb, 0.f);
                H1[(size_t)(orow0 + r) * D + col] = f2bf(v);
            }
        }
    }
}

// ---------------- GEMM2: out = h1 @ W2 + b2 (fp32) + fused BN stats (W2 in LDS) ----------------
__global__ __launch_bounds__(256, 4)
void gemm2_kernel(const ushort* __restrict__ H1, const ushort* __restrict__ Wp,
                  const float* __restrict__ bias, float* __restrict__ out,
                  float* __restrict__ stats, int nTiles) {
    __shared__ ushort Ws[16384];   // 32 KB
    __shared__ float sred[256];
    sred[threadIdx.x] = 0.f;
    {
        const float4* g = (const float4*)Wp;
        float4* l = (float4*)Ws;
        for (int i = threadIdx.x; i < 2048; i += 256) l[i] = g[i];
    }
    __syncthreads();
    int wave = threadIdx.x >> 6, lane = threadIdx.x & 63;
    int rsel = lane & 15;
    int csel = lane >> 4;
    for (int tile = blockIdx.x * 4 + wave; tile < nTiles; tile += gridDim.x * 4) {
        int row0 = tile * 16;
        const ushort* aP = H1 + (size_t)(row0 + rsel) * D + csel * 8;
        f32x4 acc[8];
        #pragma unroll
        for (int nf = 0; nf < 8; ++nf) acc[nf] = (f32x4){0.f, 0.f, 0.f, 0.f};
        #pragma unroll
        for (int ks = 0; ks < 4; ++ks) {
            s16x8 a = *(const s16x8*)(aP + ks * 32);
            #pragma unroll
            for (int nf = 0; nf < 8; ++nf) {
                s16x8 b = *(const s16x8*)(&Ws[((ks * 8 + nf) * 64 + lane) * 8]);
                acc[nf] = __builtin_amdgcn_mfma_f32_16x16x32_bf16(a, b, acc[nf], 0, 0, 0);
            }
        }
        int orow0 = row0 + csel * 4;
        #pragma unroll
        for (int nf = 0; nf < 8; ++nf) {
            int col = nf * 16 + rsel;
            float bb = bias[col];
            float ps = 0.f, pq = 0.f;
            #pragma unroll
            for (int r = 0; r < 4; ++r) {
                float v = acc[nf][r] + bb;
                out[(size_t)(orow0 + r) * D + col] = v;
                ps += v; pq += v * v;
            }
            ps += __shfl_xor(ps, 16); ps += __shfl_xor(ps, 32);
            pq += __shfl_xor(pq, 16); pq += __shfl_xor(pq, 32);
            if (csel == 0) {
                atomicAdd(&sred[col], ps);
                atomicAdd(&sred[128 + col], pq);
            }
        }
    }
    __syncthreads();
    if (threadIdx.x < 256) atomicAdd(&stats[threadIdx.x], sred[threadIdx.x]);
}

// ---------------- BN normalize + residual ----------------
__global__ void bn_final(float4* __restrict__ out4, const float4* __restrict__ x4,
                         const float* __restrict__ stats, const float* __restrict__ gamma,
                         const float* __restrict__ beta, int n4, float invN) {
    int i = blockIdx.x * blockDim.x + threadIdx.x;
    if (i >= n4) return;
    int cc = i & 31;
    const float4* s4 = (const float4*)stats;
    float4 sum = s4[cc], sq = s4[32 + cc];
    float4 g = ((const float4*)gamma)[cc], b = ((const float4*)beta)[cc];
    float4 h = out4[i], xx = x4[i];
    float4 o;
    {
        float m = sum.x * invN, v = sq.x * invN - m * m, iv = rsqrtf(v + 1e-5f);
        o.x = (h.x - m) * iv * g.x + b.x + xx.x;
    }
    {
        float m = sum.y * invN, v = sq.y * invN - m * m, iv = rsqrtf(v + 1e-5f);
        o.y = (h.y - m) * iv * g.y + b.y + xx.y;
    }
    {
        float m = sum.z * invN, v = sq.z * invN - m * m, iv = rsqrtf(v + 1e-5f);
        o.z = (h.z - m) * iv * g.z + b.z + xx.z;
    }
    {
        float m = sum.w * invN, v = sq.w * invN - m * m, iv = rsqrtf(v + 1e-5f);
        o.w = (h.w - m) * iv * g.w + b.w + xx.w;
    }
    out4[i] = o;
}

extern "C" void kernel_launch(void* const* d_in, const int* in_sizes, int n_in,
                              void* d_out, int out_size, void* d_ws, size_t ws_size,
                              hipStream_t stream) {
    const float* x     = (const float*)d_in[0];
    const int*   ei    = (const int*)d_in[1];
    const float* W1    = (const float*)d_in[2];
    const float* b1    = (const float*)d_in[3];
    const float* W2    = (const float*)d_in[4];
    const float* b2    = (const float*)d_in[5];
    const float* gamma = (const float*)d_in[6];
    const float* beta  = (const float*)d_in[7];
    float* out = (float*)d_out;

    int N = in_sizes[0] / D;   // 50000
    int E = in_sizes[1] / 2;   // 600000
    const int* src = ei;
    const int* dst = ei + E;

    size_t NB = (size_t)N * D;
    ushort* xh   = (ushort*)d_ws;          // NB ushorts
    ushort* z    = xh + NB;                // NB ushorts
    ushort* h1   = z + NB;                 // NB ushorts
    ushort* wp   = h1 + NB;                // 2*16384
    float*  stats = (float*)(wp + 32768);  // 256 floats (16B aligned)
    int*    cnt  = (int*)(stats + 256);    // N
    int*    tot  = cnt + N;                // 1
    int*    startA = tot + 1;              // N
    int*    cur  = startA + N;             // N
    int*    bucket = cur + N;              // E

    hipMemsetAsync(stats, 0, (size_t)(256 + N + 1) * sizeof(int), stream);

    const int B = 256;
    int n4 = (int)(NB / 4);
    prep_kernel<<<2048, B, 0, stream>>>((const float4*)x, (ushort4*)xh, n4,
                                        dst, cnt, E, W1, W2, wp);
    alloc_kernel<<<(N + B - 1) / B, B, 0, stream>>>(cnt, startA, cur, tot, N);
    fill_kernel<<<(E + B - 1) / B, B, 0, stream>>>(src, dst, cur, bucket, E);
    gather_kernel<<<(N + 15) / 16, B, 0, stream>>>((const u16x8*)xh, startA, cnt, bucket,
                                                   (u16x8*)z, N);
    int nTiles = (N + 15) / 16;   // 3125
    gemm1_kernel<<<782, B, 0, stream>>>(z, wp, b1, h1, nTiles);
    gemm2_kernel<<<782, B, 0, stream>>>(h1, wp + 16384, b2, out, stats, nTiles);
    bn_final<<<(n4 + B - 1) / B, B, 0, stream>>>((float4*)out, (const float4*)x, stats,
                                                 gamma, beta, n4, 1.0f / (float)N);
}